// Round 2
// baseline (751.024 us; speedup 1.0000x reference)
//
#include <hip/hip_runtime.h>

typedef __bf16 bf16;
typedef __bf16 bf16x8 __attribute__((ext_vector_type(8)));
typedef float  f32x4  __attribute__((ext_vector_type(4)));

#define C_    384
#define V_    32768
#define NTOT  12582912.0f   // 384*32768 elements per batch for GroupNorm
#define EPS_  1e-5f
#define WMAT  147456        // 384*384

// ---- async global->LDS, 16B per lane ----
__device__ __forceinline__ void g2l16(const void* g, void* l) {
    __builtin_amdgcn_global_load_lds(
        (const __attribute__((address_space(1))) void*)g,
        (__attribute__((address_space(3))) void*)l, 16, 0, 0);
}

// NaN-safe tanh-approx GELU: x * 0.5*(1+tanh(t)) = x / (1 + exp(-2t))
__device__ __forceinline__ float gelu_t(float x) {
    float u = -1.5957691216f * x * (1.0f + 0.044715f * x * x);
    return x / (1.0f + __expf(u));
}

__device__ __forceinline__ float wave_sum(float v) {
#pragma unroll
    for (int off = 32; off > 0; off >>= 1) v += __shfl_down(v, off, 64);
    return v;
}

__device__ __forceinline__ bf16x8 bz8() {
    bf16x8 z;
#pragma unroll
    for (int e = 0; e < 8; e++) z[e] = (bf16)0.f;
    return z;
}

// =================== P1: weights fp32 -> bf16 (w1,w21,w22,w23) ===================
__global__ void k_wcast(const float* __restrict__ w1, const float* __restrict__ w21,
                        const float* __restrict__ w22, const float* __restrict__ w23,
                        bf16* __restrict__ wb) {
    int i = (blockIdx.x * 256 + threadIdx.x) * 4;
    const float* srcs[4] = {w1, w21, w22, w23};
    int t = i / WMAT;
    int j = i - t * WMAT;
    const float4 v = *(const float4*)(srcs[t] + j);
    bf16* d = wb + i;
    d[0] = (bf16)v.x; d[1] = (bf16)v.y; d[2] = (bf16)v.z; d[3] = (bf16)v.w;
}

// =================== P2: x [b][c][v] fp32 -> xb [b][v][c] bf16 ===================
__global__ void k_txp(const float* __restrict__ x, bf16* __restrict__ xb) {
    __shared__ float tile[32][65];
    int bid = blockIdx.x;                   // 2 * 512 * 12
    int cb = bid % 12;
    int vb = (bid / 12) & 511;
    int b  = bid / (12 * 512);
    int c0 = cb * 32, v0 = vb * 64;
    int t = threadIdx.x;
    int vl = t & 63, cl = t >> 6;
    const float* src = x + ((size_t)(b * C_ + c0)) * V_ + v0;
#pragma unroll
    for (int i = 0; i < 8; i++)
        tile[cl + i * 4][vl] = src[(size_t)(cl + i * 4) * V_ + vl];
    __syncthreads();
    int vl2 = t >> 2, cl2 = (t & 3) * 8;
    bf16x8 o;
#pragma unroll
    for (int j = 0; j < 8; j++) o[j] = (bf16)tile[cl2 + j][vl2];
    *(bf16x8*)(xb + ((size_t)(b * V_ + v0 + vl2)) * C_ + c0 + cl2) = o;
}

// =================== shared MFMA GEMM core: 128x128 tile, K=384, BK=64 ===================
// LDS layout: row-major [128 rows][64 ch] (128B rows), 16B chunk p of row r holds
// global chunk p^(r&7)  -> bank-conflict-free ds_read_b128.
__device__ __forceinline__ void gemm_core64(const bf16* __restrict__ A, const bf16* __restrict__ Bw,
                                            bf16* sA, bf16* sB, f32x4 acc[4][4]) {
    const int tid  = threadIdx.x;
    const int lane = tid & 63;
    const int wv   = tid >> 6;
    const int wm   = (wv & 1) * 64, wn = (wv >> 1) * 64;
    const int lrow = lane & 15;
    const int q    = lane >> 4;
    const int row_l = tid >> 3;                        // 0..31 staging row
    const int kcs   = (tid & 7) ^ (row_l & 7);         // swizzled source chunk
    const bf16* ga = A  + row_l * C_ + kcs * 8;
    const bf16* gb = Bw + row_l * C_ + kcs * 8;
    char* la = (char*)sA + tid * 16;
    char* lb = (char*)sB + tid * 16;
    const char* ra = (const char*)sA;
    const char* rb = (const char*)sB;
#pragma unroll
    for (int s = 0; s < 6; s++) {
        int off = s * 64;
        __syncthreads();
#pragma unroll
        for (int j = 0; j < 4; j++) {
            g2l16(ga + off + j * 32 * C_, la + j * 4096);
            g2l16(gb + off + j * 32 * C_, lb + j * 4096);
        }
        __syncthreads();
#pragma unroll
        for (int t = 0; t < 2; t++) {
            bf16x8 af[4], bfr[4];
#pragma unroll
            for (int i = 0; i < 4; i++) {
                int r = wm + i * 16 + lrow;
                af[i] = *(const bf16x8*)(ra + r * 128 + (((t * 4 + q) ^ (r & 7)) * 16));
            }
#pragma unroll
            for (int i = 0; i < 4; i++) {
                int r = wn + i * 16 + lrow;
                bfr[i] = *(const bf16x8*)(rb + r * 128 + (((t * 4 + q) ^ (r & 7)) * 16));
            }
#pragma unroll
            for (int mi = 0; mi < 4; mi++)
#pragma unroll
                for (int ni = 0; ni < 4; ni++)
                    acc[mi][ni] = __builtin_amdgcn_mfma_f32_16x16x32_bf16(
                        af[mi], bfr[ni], acc[mi][ni], 0, 0, 0);
        }
    }
}

// Same core but A-tile is gathered with a per-K-slice row shift (fused axial shift):
// slices 0-1 (ch 0-127): +rp rows, 2-3: 0, 4-5: -|rm| rows. Invalid output rows get
// zeroed A-fragments (reference zero-pad semantics).
__device__ __forceinline__ void gemm_core64_shift(const bf16* __restrict__ A, const bf16* __restrict__ Bw,
                                                  bf16* sA, bf16* sB, f32x4 acc[4][4],
                                                  int rp, int rm,
                                                  const bool okp[4], const bool okm[4]) {
    const int tid  = threadIdx.x;
    const int lane = tid & 63;
    const int wv   = tid >> 6;
    const int wm   = (wv & 1) * 64, wn = (wv >> 1) * 64;
    const int lrow = lane & 15;
    const int q    = lane >> 4;
    const int row_l = tid >> 3;
    const int kcs   = (tid & 7) ^ (row_l & 7);
    const bf16* ga = A  + row_l * C_ + kcs * 8;
    const bf16* gb = Bw + row_l * C_ + kcs * 8;
    char* la = (char*)sA + tid * 16;
    char* lb = (char*)sB + tid * 16;
    const char* ra = (const char*)sA;
    const char* rb = (const char*)sB;
    const bf16x8 z = bz8();
#pragma unroll
    for (int s = 0; s < 6; s++) {
        int dl  = (s < 2) ? rp : (s >= 4 ? rm : 0);
        int off = s * 64 + dl * C_;
        __syncthreads();
#pragma unroll
        for (int j = 0; j < 4; j++) {
            g2l16(ga + off + j * 32 * C_, la + j * 4096);
            g2l16(gb + s * 64 + j * 32 * C_, lb + j * 4096);
        }
        __syncthreads();
#pragma unroll
        for (int t = 0; t < 2; t++) {
            bf16x8 af[4], bfr[4];
#pragma unroll
            for (int i = 0; i < 4; i++) {
                int r = wm + i * 16 + lrow;
                af[i] = *(const bf16x8*)(ra + r * 128 + (((t * 4 + q) ^ (r & 7)) * 16));
                if (s < 2)       { if (!okp[i]) af[i] = z; }
                else if (s >= 4) { if (!okm[i]) af[i] = z; }
            }
#pragma unroll
            for (int i = 0; i < 4; i++) {
                int r = wn + i * 16 + lrow;
                bfr[i] = *(const bf16x8*)(rb + r * 128 + (((t * 4 + q) ^ (r & 7)) * 16));
            }
#pragma unroll
            for (int mi = 0; mi < 4; mi++)
#pragma unroll
                for (int ni = 0; ni < 4; ni++)
                    acc[mi][ni] = __builtin_amdgcn_mfma_f32_16x16x32_bf16(
                        af[mi], bfr[ni], acc[mi][ni], 0, 0, 0);
        }
    }
}

__device__ __forceinline__ void tile_coords(int bid, int& b, int& m0, int& n0) {
    b = bid / 768;
    int r = bid % 768;
    m0 = (r / 3) * 128;
    n0 = (r % 3) * 128;
}

#define ZERO_ACC(acc) \
    _Pragma("unroll") for (int i = 0; i < 4; i++) \
    _Pragma("unroll") for (int j = 0; j < 4; j++) \
    _Pragma("unroll") for (int r = 0; r < 4; r++) acc[i][j][r] = 0.f;

// =================== P3: GEMM1 = xb @ w1 + b1 -> h1 bf16, + GN1 stats ===================
__global__ __launch_bounds__(256, 3) void k_gemm1(const bf16* __restrict__ xb, const bf16* __restrict__ w1b,
                                                  const float* __restrict__ b1, bf16* __restrict__ h1,
                                                  float* __restrict__ stats) {
    __shared__ bf16 sA[128 * 64], sB[128 * 64];
    int b, m0, n0; tile_coords(blockIdx.x, b, m0, n0);
    f32x4 acc[4][4];
    ZERO_ACC(acc)
    gemm_core64(xb + ((size_t)(b * V_) + m0) * C_, w1b + n0 * C_, sA, sB, acc);
    int lane = threadIdx.x & 63, wv = threadIdx.x >> 6;
    int wm = (wv & 1) * 64, wn = (wv >> 1) * 64;
    int col = lane & 15, rowq = (lane >> 4) * 4;
    float s = 0.f, ss = 0.f;
#pragma unroll
    for (int ni = 0; ni < 4; ni++) {
        int o = n0 + wn + ni * 16 + col;
        float bias = b1[o];
#pragma unroll
        for (int mi = 0; mi < 4; mi++) {
            size_t vb = (size_t)(b * V_) + m0 + wm + mi * 16 + rowq;
#pragma unroll
            for (int rg = 0; rg < 4; rg++) {
                float val = acc[mi][ni][rg] + bias;
                s += val; ss += val * val;
                h1[(vb + rg) * C_ + o] = (bf16)val;
            }
        }
    }
    s = wave_sum(s); ss = wave_sum(ss);
    if (lane == 0) { atomicAdd(&stats[2 * b], s); atomicAdd(&stats[2 * b + 1], ss); }
}

// =================== P4: GN1 + GELU -> g (single tensor; shifts fused into GEMM2) ===========
__global__ void k_act(const bf16* __restrict__ h1, const float* __restrict__ g1,
                      const float* __restrict__ bt1, const float* __restrict__ stats,
                      bf16* __restrict__ g) {
    int idx = blockIdx.x * 256 + threadIdx.x;   // 2*32768*48 threads
    int cg = idx % 48;
    int t2 = idx / 48;
    int v = t2 & (V_ - 1);
    int b = t2 >> 15;
    float inv  = 1.0f / NTOT;
    float mean = stats[2 * b] * inv;
    float var  = stats[2 * b + 1] * inv - mean * mean;
    float rstd = rsqrtf(var + EPS_);
    int c0 = cg * 8;
    float a[8], be[8];
    {
        const float4 gA = *(const float4*)(g1 + c0);
        const float4 gB = *(const float4*)(g1 + c0 + 4);
        const float4 bA = *(const float4*)(bt1 + c0);
        const float4 bB = *(const float4*)(bt1 + c0 + 4);
        float gg[8] = {gA.x, gA.y, gA.z, gA.w, gB.x, gB.y, gB.z, gB.w};
        float bb[8] = {bA.x, bA.y, bA.z, bA.w, bB.x, bB.y, bB.z, bB.w};
#pragma unroll
        for (int e = 0; e < 8; e++) { a[e] = rstd * gg[e]; be[e] = bb[e] - mean * a[e]; }
    }
    size_t off = ((size_t)b * V_ + v) * C_ + c0;
    bf16x8 xin = *(const bf16x8*)(h1 + off);
    bf16x8 outv;
#pragma unroll
    for (int e = 0; e < 8; e++) outv[e] = (bf16)gelu_t((float)xin[e] * a[e] + be[e]);
    *(bf16x8*)(g + off) = outv;
}

// =================== P5: fused GEMM2 (3 shifted branches from g) + GN2 stats ===================
__global__ __launch_bounds__(256, 2) void k_gemm2(const bf16* __restrict__ g, const bf16* __restrict__ wb,
                                                  const float* __restrict__ b21, const float* __restrict__ b22,
                                                  const float* __restrict__ b23, bf16* __restrict__ y,
                                                  float* __restrict__ stats) {
    __shared__ bf16 sA[128 * 64], sB[128 * 64];
    int b, m0, n0; tile_coords(blockIdx.x, b, m0, n0);
    int lane = threadIdx.x & 63, wv = threadIdx.x >> 6;
    int wm = (wv & 1) * 64, wn = (wv >> 1) * 64;
    int col = lane & 15, rowq = (lane >> 4) * 4;
    int lrow = lane & 15;

    // validity of shifted source per output row (zero-pad at axis boundary)
    int d0 = m0 >> 10;                         // D coord: uniform across 128-row tile
    bool tdp = d0 < 31, tdm = d0 > 0;
    bool okp_td[4], okm_td[4], okp_lr[4], okm_lr[4], okp_hd[4], okm_hd[4];
#pragma unroll
    for (int mi = 0; mi < 4; mi++) {
        int r = wm + mi * 16 + lrow;
        int hh = ((m0 + r) >> 5) & 31;
        int w  = r & 31;
        okp_td[mi] = tdp;      okm_td[mi] = tdm;
        okp_lr[mi] = hh < 31;  okm_lr[mi] = hh > 0;
        okp_hd[mi] = w < 31;   okm_hd[mi] = w > 0;
    }
    const bf16* gA = g + ((size_t)(b * V_) + m0) * C_;

    f32x4 yac[4][4];
    ZERO_ACC(yac)

    // branch order per reference: lr (H, stride 32, w21), td (D, stride 1024, w22), hd (W, stride 1, w23)
#pragma unroll
    for (int ax = 0; ax < 3; ax++) {
        f32x4 acc[4][4];
        ZERO_ACC(acc)
        if (ax == 0)
            gemm_core64_shift(gA, wb + WMAT + n0 * C_, sA, sB, acc, 32, -32, okp_lr, okm_lr);
        else if (ax == 1)
            gemm_core64_shift(gA, wb + 2 * WMAT + n0 * C_, sA, sB, acc,
                              tdp ? 1024 : 0, tdm ? -1024 : 0, okp_td, okm_td);
        else
            gemm_core64_shift(gA, wb + 3 * WMAT + n0 * C_, sA, sB, acc, 1, -1, okp_hd, okm_hd);
        const float* bs = (ax == 0) ? b21 : (ax == 1) ? b22 : b23;
#pragma unroll
        for (int ni = 0; ni < 4; ni++) {
            float bias = bs[n0 + wn + ni * 16 + col];
#pragma unroll
            for (int mi = 0; mi < 4; mi++)
#pragma unroll
                for (int rg = 0; rg < 4; rg++)
                    yac[mi][ni][rg] += gelu_t(acc[mi][ni][rg] + bias);
        }
    }
    float s = 0.f, ss = 0.f;
#pragma unroll
    for (int ni = 0; ni < 4; ni++) {
        int o = n0 + wn + ni * 16 + col;
#pragma unroll
        for (int mi = 0; mi < 4; mi++) {
            size_t vb = (size_t)(b * V_) + m0 + wm + mi * 16 + rowq;
#pragma unroll
            for (int rg = 0; rg < 4; rg++) {
                float val = yac[mi][ni][rg];
                s += val; ss += val * val;
                y[(vb + rg) * C_ + o] = (bf16)val;
            }
        }
    }
    s = wave_sum(s); ss = wave_sum(ss);
    if (lane == 0) { atomicAdd(&stats[4 + 2 * b], s); atomicAdd(&stats[5 + 2 * b], ss); }
}

// =================== P6: fold GN2 affine into W3/b3 (per batch) ===================
__global__ void k_fold(const float* __restrict__ w3, const float* __restrict__ b3,
                       const float* __restrict__ g2, const float* __restrict__ bt2,
                       const float* __restrict__ stats, bf16* __restrict__ w3p,
                       float* __restrict__ b3p) {
    int bo = blockIdx.x;           // 768 = 2*384
    int b = bo / 384, o = bo % 384;
    int l = threadIdx.x;           // 64 threads
    float inv  = 1.0f / NTOT;
    float mean = stats[4 + 2 * b] * inv;
    float var  = stats[5 + 2 * b] * inv - mean * mean;
    float rstd = rsqrtf(var + EPS_);
    float part = 0.f;
    for (int c = l; c < C_; c += 64) {
        float wv_ = w3[o * C_ + c];
        float gr  = g2[c] * rstd;
        w3p[(size_t)b * WMAT + o * C_ + c] = (bf16)(wv_ * gr);
        part += wv_ * (bt2[c] - mean * gr);
    }
    part = wave_sum(part);
    if (l == 0) b3p[bo] = b3[o] + part;
}

// =================== P7: GEMM3 -> d_out fp32, channel-first layout ===================
__global__ __launch_bounds__(256, 3) void k_gemm3(const bf16* __restrict__ y, const bf16* __restrict__ w3p,
                                                  const float* __restrict__ b3p, float* __restrict__ out) {
    __shared__ bf16 sA[128 * 64], sB[128 * 64];
    int b, m0, n0; tile_coords(blockIdx.x, b, m0, n0);
    f32x4 acc[4][4];
    ZERO_ACC(acc)
    gemm_core64(y + ((size_t)(b * V_) + m0) * C_, w3p + (size_t)b * WMAT + n0 * C_, sA, sB, acc);
    int lane = threadIdx.x & 63, wv = threadIdx.x >> 6;
    int wm = (wv & 1) * 64, wn = (wv >> 1) * 64;
    int col = lane & 15, rowq = (lane >> 4) * 4;
#pragma unroll
    for (int ni = 0; ni < 4; ni++) {
        int o = n0 + wn + ni * 16 + col;
        float bias = b3p[b * C_ + o];
#pragma unroll
        for (int mi = 0; mi < 4; mi++) {
            f32x4 r = acc[mi][ni];
            r[0] += bias; r[1] += bias; r[2] += bias; r[3] += bias;
            size_t adr = (size_t)b * ((size_t)C_ * V_) + (size_t)o * V_ + (m0 + wm + mi * 16 + rowq);
            *(f32x4*)(out + adr) = r;
        }
    }
}

extern "C" void kernel_launch(void* const* d_in, const int* in_sizes, int n_in,
                              void* d_out, int out_size, void* d_ws, size_t ws_size,
                              hipStream_t stream) {
    const float* x   = (const float*)d_in[0];
    const float* w1  = (const float*)d_in[1];
    const float* b1  = (const float*)d_in[2];
    const float* g1  = (const float*)d_in[3];
    const float* bt1 = (const float*)d_in[4];
    const float* w21 = (const float*)d_in[5];
    const float* b21 = (const float*)d_in[6];
    const float* w22 = (const float*)d_in[7];
    const float* b22 = (const float*)d_in[8];
    const float* w23 = (const float*)d_in[9];
    const float* b23 = (const float*)d_in[10];
    const float* g2  = (const float*)d_in[11];
    const float* bt2 = (const float*)d_in[12];
    const float* w3  = (const float*)d_in[13];
    const float* b3  = (const float*)d_in[14];
    float* out = (float*)d_out;

    char* ws = (char*)d_ws;
    const size_t HALF = 50331648ull;                    // one bf16 tensor (2*384*32768*2 B)
    bf16*  xb  = (bf16*)ws;                             // xb (P2-P3), then y (P5-P7)
    bf16*  g   = (bf16*)(ws + HALF + 32768);            // 32KB pre-guard for shifted staging reads
    char*  tail = ws + 2 * HALF + 65536;                // 32KB post-guard (gap before tail)
    bf16*  wb    = (bf16*)tail;                         // 1,179,648 B
    bf16*  w3p   = (bf16*)(tail + 1179648);             //   589,824 B
    float* b3p   = (float*)(tail + 1179648 + 589824);   //     3,072 B
    float* stats = (float*)(tail + 1179648 + 589824 + 3072);
    bf16*  h1 = (bf16*)d_out;                           // d_out first half as scratch (dead before P7)
    bf16*  y  = xb;

    hipMemsetAsync(stats, 0, 64, stream);
    k_wcast<<<576,   256, 0, stream>>>(w1, w21, w22, w23, wb);
    k_txp  <<<12288, 256, 0, stream>>>(x, xb);
    k_gemm1<<<1536,  256, 0, stream>>>(xb, wb, b1, h1, stats);
    k_act  <<<12288, 256, 0, stream>>>(h1, g1, bt1, stats, g);
    k_gemm2<<<1536,  256, 0, stream>>>(g, wb, b21, b22, b23, y, stats);
    k_fold <<<768,    64, 0, stream>>>(w3, b3, g2, bt2, stats, w3p, b3p);
    k_gemm3<<<1536,  256, 0, stream>>>(y, w3p, b3p, out);
}

// Round 3
// 637.771 us; speedup vs baseline: 1.1776x; 1.1776x over previous
//
#include <hip/hip_runtime.h>

typedef __bf16 bf16;
typedef __bf16 bf16x8 __attribute__((ext_vector_type(8)));
typedef float  f32x4  __attribute__((ext_vector_type(4)));

#define C_    384
#define V_    32768
#define NTOT  12582912.0f   // 384*32768 elements per batch for GroupNorm
#define EPS_  1e-5f
#define WMAT  147456        // 384*384

// ---- async global->LDS, 16B per lane (per-lane global src address is legal) ----
__device__ __forceinline__ void g2l16(const void* g, void* l) {
    __builtin_amdgcn_global_load_lds(
        (const __attribute__((address_space(1))) void*)g,
        (__attribute__((address_space(3))) void*)l, 16, 0, 0);
}

// NaN-safe tanh-approx GELU: x * 0.5*(1+tanh(t)) = x / (1 + exp(-2t))
__device__ __forceinline__ float gelu_t(float x) {
    float u = -1.5957691216f * x * (1.0f + 0.044715f * x * x);
    return x / (1.0f + __expf(u));
}

__device__ __forceinline__ float wave_sum(float v) {
#pragma unroll
    for (int off = 32; off > 0; off >>= 1) v += __shfl_down(v, off, 64);
    return v;
}

// =================== P1: weights fp32 -> bf16 (w1,w21,w22,w23) ===================
__global__ void k_wcast(const float* __restrict__ w1, const float* __restrict__ w21,
                        const float* __restrict__ w22, const float* __restrict__ w23,
                        bf16* __restrict__ wb) {
    int i = (blockIdx.x * 256 + threadIdx.x) * 4;
    const float* srcs[4] = {w1, w21, w22, w23};
    int t = i / WMAT;
    int j = i - t * WMAT;
    const float4 v = *(const float4*)(srcs[t] + j);
    bf16* d = wb + i;
    d[0] = (bf16)v.x; d[1] = (bf16)v.y; d[2] = (bf16)v.z; d[3] = (bf16)v.w;
}

// =================== P2: x [b][c][v] fp32 -> xb [b][v][c] bf16 ===================
__global__ void k_txp(const float* __restrict__ x, bf16* __restrict__ xb) {
    __shared__ float tile[32][65];
    int bid = blockIdx.x;                   // 2 * 512 * 12
    int cb = bid % 12;
    int vb = (bid / 12) & 511;
    int b  = bid / (12 * 512);
    int c0 = cb * 32, v0 = vb * 64;
    int t = threadIdx.x;
    int vl = t & 63, cl = t >> 6;
    const float* src = x + ((size_t)(b * C_ + c0)) * V_ + v0;
#pragma unroll
    for (int i = 0; i < 8; i++)
        tile[cl + i * 4][vl] = src[(size_t)(cl + i * 4) * V_ + vl];
    __syncthreads();
    int vl2 = t >> 2, cl2 = (t & 3) * 8;
    bf16x8 o;
#pragma unroll
    for (int j = 0; j < 8; j++) o[j] = (bf16)tile[cl2 + j][vl2];
    *(bf16x8*)(xb + ((size_t)(b * V_ + v0 + vl2)) * C_ + c0 + cl2) = o;
}

// XCD-aware tile map: bid&7 ~ XCD; each XCD owns a contiguous 64-m-tile range,
// n fastest so the 3 n-blocks of one m-tile are temporally adjacent on one XCD.
__device__ __forceinline__ void tile_coords(int bid, int& b, int& m0, int& n0) {
    int x = bid & 7, gq = bid >> 3;        // gq in [0,192)
    n0 = (gq % 3) * 128;
    int mt = x * 64 + gq / 3;              // 512 m-tiles (2 batches x 256)
    b  = mt >> 8;
    m0 = (mt & 255) * 128;
}

#define ZERO_ACC(acc) \
    _Pragma("unroll") for (int i = 0; i < 4; i++) \
    _Pragma("unroll") for (int j = 0; j < 4; j++) \
    _Pragma("unroll") for (int r = 0; r < 4; r++) acc[i][j][r] = 0.f;

// =================== MFMA GEMM core: 128x128 tile, K=384, BK=64, XOR-swizzled LDS ============
// LDS: row-major [128 rows][64 ch] (128B rows); 16B chunk c of row r holds global chunk c^(r&7).
__device__ __forceinline__ void gemm_core64(const bf16* __restrict__ A, const bf16* __restrict__ Bw,
                                            bf16* sA, bf16* sB, f32x4 acc[4][4]) {
    const int tid  = threadIdx.x;
    const int lane = tid & 63;
    const int wv   = tid >> 6;
    const int wm   = (wv & 1) * 64, wn = (wv >> 1) * 64;
    const int lrow = lane & 15;
    const int q    = lane >> 4;
    const int row_l = tid >> 3;
    const int kcs   = (tid & 7) ^ (row_l & 7);
    const bf16* ga = A  + row_l * C_ + kcs * 8;
    const bf16* gb = Bw + row_l * C_ + kcs * 8;
    char* la = (char*)sA + tid * 16;
    char* lb = (char*)sB + tid * 16;
    const char* ra = (const char*)sA;
    const char* rb = (const char*)sB;
#pragma unroll
    for (int s = 0; s < 6; s++) {
        int off = s * 64;
        __syncthreads();
#pragma unroll
        for (int j = 0; j < 4; j++) {
            g2l16(ga + off + j * 32 * C_, la + j * 4096);
            g2l16(gb + off + j * 32 * C_, lb + j * 4096);
        }
        __syncthreads();
#pragma unroll
        for (int t = 0; t < 2; t++) {
            bf16x8 af[4], bfr[4];
#pragma unroll
            for (int i = 0; i < 4; i++) {
                int r = wm + i * 16 + lrow;
                af[i] = *(const bf16x8*)(ra + r * 128 + (((t * 4 + q) ^ (r & 7)) * 16));
            }
#pragma unroll
            for (int i = 0; i < 4; i++) {
                int r = wn + i * 16 + lrow;
                bfr[i] = *(const bf16x8*)(rb + r * 128 + (((t * 4 + q) ^ (r & 7)) * 16));
            }
#pragma unroll
            for (int mi = 0; mi < 4; mi++)
#pragma unroll
                for (int ni = 0; ni < 4; ni++)
                    acc[mi][ni] = __builtin_amdgcn_mfma_f32_16x16x32_bf16(
                        af[mi], bfr[ni], acc[mi][ni], 0, 0, 0);
        }
    }
}

// Shifted-A variant: per-K-slice-group A source pointers (validity pre-resolved to a
// zero page — invalid rows read zeros, never touch out-of-range memory).
__device__ __forceinline__ void gemm_core64_zp(const bf16* const pc[4], const bf16* const pp[4],
                                               const bf16* const pm[4], const bf16* __restrict__ Bw,
                                               bf16* sA, bf16* sB, f32x4 acc[4][4]) {
    const int tid  = threadIdx.x;
    const int lane = tid & 63;
    const int wv   = tid >> 6;
    const int wm   = (wv & 1) * 64, wn = (wv >> 1) * 64;
    const int lrow = lane & 15;
    const int q    = lane >> 4;
    const int row_l = tid >> 3;
    const int kcs   = (tid & 7) ^ (row_l & 7);
    const bf16* gb = Bw + row_l * C_ + kcs * 8;
    char* la = (char*)sA + tid * 16;
    char* lb = (char*)sB + tid * 16;
    const char* ra = (const char*)sA;
    const char* rb = (const char*)sB;
#pragma unroll
    for (int s = 0; s < 6; s++) {
        int off = s * 64;
        const bf16* const* arr = (s < 2) ? pp : ((s < 4) ? pc : pm);
        __syncthreads();
#pragma unroll
        for (int j = 0; j < 4; j++) {
            g2l16(arr[j] + off, la + j * 4096);
            g2l16(gb + off + j * 32 * C_, lb + j * 4096);
        }
        __syncthreads();
#pragma unroll
        for (int t = 0; t < 2; t++) {
            bf16x8 af[4], bfr[4];
#pragma unroll
            for (int i = 0; i < 4; i++) {
                int r = wm + i * 16 + lrow;
                af[i] = *(const bf16x8*)(ra + r * 128 + (((t * 4 + q) ^ (r & 7)) * 16));
            }
#pragma unroll
            for (int i = 0; i < 4; i++) {
                int r = wn + i * 16 + lrow;
                bfr[i] = *(const bf16x8*)(rb + r * 128 + (((t * 4 + q) ^ (r & 7)) * 16));
            }
#pragma unroll
            for (int mi = 0; mi < 4; mi++)
#pragma unroll
                for (int ni = 0; ni < 4; ni++)
                    acc[mi][ni] = __builtin_amdgcn_mfma_f32_16x16x32_bf16(
                        af[mi], bfr[ni], acc[mi][ni], 0, 0, 0);
        }
    }
}

// =================== P3: GEMM1 = xb @ w1 + b1 -> h1 bf16, + GN1 stats ===================
__global__ __launch_bounds__(256, 3) void k_gemm1(const bf16* __restrict__ xb, const bf16* __restrict__ w1b,
                                                  const float* __restrict__ b1, bf16* __restrict__ h1,
                                                  float* __restrict__ stats) {
    __shared__ bf16 sA[128 * 64], sB[128 * 64];
    int b, m0, n0; tile_coords(blockIdx.x, b, m0, n0);
    f32x4 acc[4][4];
    ZERO_ACC(acc)
    gemm_core64(xb + ((size_t)(b * V_) + m0) * C_, w1b + n0 * C_, sA, sB, acc);
    int lane = threadIdx.x & 63, wv = threadIdx.x >> 6;
    int wm = (wv & 1) * 64, wn = (wv >> 1) * 64;
    int col = lane & 15, rowq = (lane >> 4) * 4;
    float s = 0.f, ss = 0.f;
#pragma unroll
    for (int ni = 0; ni < 4; ni++) {
        int o = n0 + wn + ni * 16 + col;
        float bias = b1[o];
#pragma unroll
        for (int mi = 0; mi < 4; mi++) {
            size_t vb = (size_t)(b * V_) + m0 + wm + mi * 16 + rowq;
#pragma unroll
            for (int rg = 0; rg < 4; rg++) {
                float val = acc[mi][ni][rg] + bias;
                s += val; ss += val * val;
                h1[(vb + rg) * C_ + o] = (bf16)val;
            }
        }
    }
    s = wave_sum(s); ss = wave_sum(ss);
    if (lane == 0) { atomicAdd(&stats[2 * b], s); atomicAdd(&stats[2 * b + 1], ss); }
}

// =================== P4: GN1 + GELU -> g ===================
__global__ void k_act(const bf16* __restrict__ h1, const float* __restrict__ g1,
                      const float* __restrict__ bt1, const float* __restrict__ stats,
                      bf16* __restrict__ g) {
    int idx = blockIdx.x * 256 + threadIdx.x;   // 2*32768*48 threads
    int cg = idx % 48;
    int t2 = idx / 48;
    int v = t2 & (V_ - 1);
    int b = t2 >> 15;
    float inv  = 1.0f / NTOT;
    float mean = stats[2 * b] * inv;
    float var  = stats[2 * b + 1] * inv - mean * mean;
    float rstd = rsqrtf(var + EPS_);
    int c0 = cg * 8;
    float a[8], be[8];
    {
        const float4 gA = *(const float4*)(g1 + c0);
        const float4 gB = *(const float4*)(g1 + c0 + 4);
        const float4 bA = *(const float4*)(bt1 + c0);
        const float4 bB = *(const float4*)(bt1 + c0 + 4);
        float gg[8] = {gA.x, gA.y, gA.z, gA.w, gB.x, gB.y, gB.z, gB.w};
        float bb[8] = {bA.x, bA.y, bA.z, bA.w, bB.x, bB.y, bB.z, bB.w};
#pragma unroll
        for (int e = 0; e < 8; e++) { a[e] = rstd * gg[e]; be[e] = bb[e] - mean * a[e]; }
    }
    size_t off = ((size_t)b * V_ + v) * C_ + c0;
    bf16x8 xin = *(const bf16x8*)(h1 + off);
    bf16x8 outv;
#pragma unroll
    for (int e = 0; e < 8; e++) outv[e] = (bf16)gelu_t((float)xin[e] * a[e] + be[e]);
    *(bf16x8*)(g + off) = outv;
}

// =================== P5: fused GEMM2 (3 shifted branches) + GN2 stats ===================
__global__ __launch_bounds__(256, 2) void k_gemm2(const bf16* __restrict__ g, const bf16* __restrict__ wb,
                                                  const float* __restrict__ b21, const float* __restrict__ b22,
                                                  const float* __restrict__ b23, bf16* __restrict__ y,
                                                  float* __restrict__ stats, const bf16* __restrict__ zp) {
    __shared__ bf16 sA[128 * 64], sB[128 * 64];
    int b, m0, n0; tile_coords(blockIdx.x, b, m0, n0);
    int lane = threadIdx.x & 63, wv = threadIdx.x >> 6;
    int wm = (wv & 1) * 64, wn = (wv >> 1) * 64;
    int col = lane & 15, rowq = (lane >> 4) * 4;
    const int row_l = threadIdx.x >> 3;
    const int kcs   = (threadIdx.x & 7) ^ (row_l & 7);
    const bf16* gA = g + ((size_t)(b * V_) + m0) * C_;
    const bf16* pc[4];
#pragma unroll
    for (int j = 0; j < 4; j++) pc[j] = gA + (row_l + j * 32) * C_ + kcs * 8;

    f32x4 yac[4][4];
    ZERO_ACC(yac)

    // branch order: lr (H, stride 32, w21), td (D, stride 1024, w22), hd (W, stride 1, w23)
#pragma unroll
    for (int ax = 0; ax < 3; ax++) {
        const bf16* pp[4];
        const bf16* pm[4];
        if (ax == 0) {
#pragma unroll
            for (int j = 0; j < 4; j++) {
                int hh = ((m0 >> 5) + j) & 31;
                pp[j] = (hh < 31) ? pc[j] + 32 * C_ : zp;
                pm[j] = (hh > 0)  ? pc[j] - 32 * C_ : zp;
            }
        } else if (ax == 1) {
            int d0 = m0 >> 10;
#pragma unroll
            for (int j = 0; j < 4; j++) {
                pp[j] = (d0 < 31) ? pc[j] + 1024 * C_ : zp;
                pm[j] = (d0 > 0)  ? pc[j] - 1024 * C_ : zp;
            }
        } else {
#pragma unroll
            for (int j = 0; j < 4; j++) {
                pp[j] = (row_l < 31) ? pc[j] + C_ : zp;
                pm[j] = (row_l > 0)  ? pc[j] - C_ : zp;
            }
        }
        f32x4 acc[4][4];
        ZERO_ACC(acc)
        gemm_core64_zp(pc, pp, pm, wb + (ax + 1) * WMAT + n0 * C_, sA, sB, acc);
        const float* bs = (ax == 0) ? b21 : (ax == 1) ? b22 : b23;
#pragma unroll
        for (int ni = 0; ni < 4; ni++) {
            float bias = bs[n0 + wn + ni * 16 + col];
#pragma unroll
            for (int mi = 0; mi < 4; mi++)
#pragma unroll
                for (int rg = 0; rg < 4; rg++)
                    yac[mi][ni][rg] += gelu_t(acc[mi][ni][rg] + bias);
        }
    }
    float s = 0.f, ss = 0.f;
#pragma unroll
    for (int ni = 0; ni < 4; ni++) {
        int o = n0 + wn + ni * 16 + col;
#pragma unroll
        for (int mi = 0; mi < 4; mi++) {
            size_t vb = (size_t)(b * V_) + m0 + wm + mi * 16 + rowq;
#pragma unroll
            for (int rg = 0; rg < 4; rg++) {
                float val = yac[mi][ni][rg];
                s += val; ss += val * val;
                y[(vb + rg) * C_ + o] = (bf16)val;
            }
        }
    }
    s = wave_sum(s); ss = wave_sum(ss);
    if (lane == 0) { atomicAdd(&stats[4 + 2 * b], s); atomicAdd(&stats[5 + 2 * b], ss); }
}

// =================== P6: fold GN2 affine into W3/b3 (per batch) ===================
__global__ void k_fold(const float* __restrict__ w3, const float* __restrict__ b3,
                       const float* __restrict__ g2, const float* __restrict__ bt2,
                       const float* __restrict__ stats, bf16* __restrict__ w3p,
                       float* __restrict__ b3p) {
    int bo = blockIdx.x;           // 768 = 2*384
    int b = bo / 384, o = bo % 384;
    int l = threadIdx.x;           // 64 threads
    float inv  = 1.0f / NTOT;
    float mean = stats[4 + 2 * b] * inv;
    float var  = stats[5 + 2 * b] * inv - mean * mean;
    float rstd = rsqrtf(var + EPS_);
    float part = 0.f;
    for (int c = l; c < C_; c += 64) {
        float wv_ = w3[o * C_ + c];
        float gr  = g2[c] * rstd;
        w3p[(size_t)b * WMAT + o * C_ + c] = (bf16)(wv_ * gr);
        part += wv_ * (bt2[c] - mean * gr);
    }
    part = wave_sum(part);
    if (l == 0) b3p[bo] = b3[o] + part;
}

// =================== P7: GEMM3 -> d_out fp32, channel-first layout ===================
__global__ __launch_bounds__(256, 3) void k_gemm3(const bf16* __restrict__ y, const bf16* __restrict__ w3p,
                                                  const float* __restrict__ b3p, float* __restrict__ out) {
    __shared__ bf16 sA[128 * 64], sB[128 * 64];
    int b, m0, n0; tile_coords(blockIdx.x, b, m0, n0);
    f32x4 acc[4][4];
    ZERO_ACC(acc)
    gemm_core64(y + ((size_t)(b * V_) + m0) * C_, w3p + (size_t)b * WMAT + n0 * C_, sA, sB, acc);
    int lane = threadIdx.x & 63, wv = threadIdx.x >> 6;
    int wm = (wv & 1) * 64, wn = (wv >> 1) * 64;
    int col = lane & 15, rowq = (lane >> 4) * 4;
#pragma unroll
    for (int ni = 0; ni < 4; ni++) {
        int o = n0 + wn + ni * 16 + col;
        float bias = b3p[b * C_ + o];
#pragma unroll
        for (int mi = 0; mi < 4; mi++) {
            f32x4 r = acc[mi][ni];
            r[0] += bias; r[1] += bias; r[2] += bias; r[3] += bias;
            size_t adr = (size_t)b * ((size_t)C_ * V_) + (size_t)o * V_ + (m0 + wm + mi * 16 + rowq);
            *(f32x4*)(out + adr) = r;
        }
    }
}

extern "C" void kernel_launch(void* const* d_in, const int* in_sizes, int n_in,
                              void* d_out, int out_size, void* d_ws, size_t ws_size,
                              hipStream_t stream) {
    const float* x   = (const float*)d_in[0];
    const float* w1  = (const float*)d_in[1];
    const float* b1  = (const float*)d_in[2];
    const float* g1  = (const float*)d_in[3];
    const float* bt1 = (const float*)d_in[4];
    const float* w21 = (const float*)d_in[5];
    const float* b21 = (const float*)d_in[6];
    const float* w22 = (const float*)d_in[7];
    const float* b22 = (const float*)d_in[8];
    const float* w23 = (const float*)d_in[9];
    const float* b23 = (const float*)d_in[10];
    const float* g2  = (const float*)d_in[11];
    const float* bt2 = (const float*)d_in[12];
    const float* w3  = (const float*)d_in[13];
    const float* b3  = (const float*)d_in[14];
    float* out = (float*)d_out;

    char* ws = (char*)d_ws;
    const size_t HALF = 50331648ull;                    // one bf16 tensor (2*384*32768*2 B)
    bf16*  xb  = (bf16*)ws;                             // xb (P2-P3), then y (P5-P7)
    bf16*  g   = (bf16*)(ws + HALF);
    char*  tail = ws + 2 * HALF;
    float* stats = (float*)tail;                        // tail[0:128)   zeroed
    bf16*  zp    = (bf16*)(tail + 2048);                // tail[2048:4096) zeroed
    bf16*  wb    = (bf16*)(tail + 4096);                // 1,179,648 B
    bf16*  w3p   = (bf16*)(tail + 4096 + 1179648);      //   589,824 B
    float* b3p   = (float*)(tail + 4096 + 1179648 + 589824);
    bf16*  h1 = (bf16*)d_out;                           // d_out first half as scratch (dead before P7)
    bf16*  y  = xb;

    hipMemsetAsync(tail, 0, 4096, stream);              // stats + zero page
    k_wcast<<<576,   256, 0, stream>>>(w1, w21, w22, w23, wb);
    k_txp  <<<12288, 256, 0, stream>>>(x, xb);
    k_gemm1<<<1536,  256, 0, stream>>>(xb, wb, b1, h1, stats);
    k_act  <<<12288, 256, 0, stream>>>(h1, g1, bt1, stats, g);
    k_gemm2<<<1536,  256, 0, stream>>>(g, wb, b21, b22, b23, y, stats, zp);
    k_fold <<<768,    64, 0, stream>>>(w3, b3, g2, bt2, stats, w3p, b3p);
    k_gemm3<<<1536,  256, 0, stream>>>(y, w3p, b3p, out);
}